// Round 10
// baseline (743.662 us; speedup 1.0000x reference)
//
#include <hip/hip_runtime.h>

#define KT 4
#define KN 20000        // NA == ND == 20000
#define KE 100000
#define KH 128
#define KL 2
#define KNT 40000       // NA + ND

typedef __attribute__((ext_vector_type(8))) short short8v;
typedef __attribute__((ext_vector_type(4))) float f32x4;

__device__ __forceinline__ short bf16rn(float x) {
    unsigned u = __float_as_uint(x);
    u = (u + 0x7fffu + ((u >> 16) & 1u)) >> 16;
    return (short)u;
}
__device__ __forceinline__ float bf16tof(short h) {
    return __uint_as_float(((unsigned)(unsigned short)h) << 16);
}

// ---------------------------------------------------------------------------
// compress_k: sequential-stream fp32 -> bf16 copy of ea (ORIGINAL edge
// order, no permutation -> no scatter; ~6 TB/s).  ea_s[z][e][f], z=t*2+et.
// ---------------------------------------------------------------------------
__global__ __launch_bounds__(256)
void compress_k(const float* __restrict__ ea_ad, const float* __restrict__ ea_da,
                unsigned short* __restrict__ ea_s) {
    int z = blockIdx.y, t = z >> 1, et = z & 1;
    const float4* in4 = (const float4*)((et ? ea_da : ea_ad) + (long)t * KE * KH);
    uint2* out2 = (uint2*)(ea_s + (long)z * KE * KH);
    const int NU = KE * (KH / 4);             // 3.2M float4 units per z
    int stride = gridDim.x * 256;
    for (int u = blockIdx.x * 256 + threadIdx.x; u < NU; u += stride) {
        float4 v = in4[u];
        unsigned w0 = (unsigned)(unsigned short)bf16rn(v.x)
                    | ((unsigned)(unsigned short)bf16rn(v.y) << 16);
        unsigned w1 = (unsigned)(unsigned short)bf16rn(v.z)
                    | ((unsigned)(unsigned short)bf16rn(v.w) << 16);
        out2[u] = make_uint2(w0, w1);
    }
}

// ---------------------------------------------------------------------------
// CSR build: counts -> scan -> fill (packed (edge, src) pairs).
// ---------------------------------------------------------------------------
__global__ void count_k(const int* __restrict__ ei_ad, const int* __restrict__ ei_da,
                        int* __restrict__ cnt) {
    int e = blockIdx.x * 256 + threadIdx.x;
    int z = blockIdx.y;                 // z = t*2 + et
    if (e >= KE) return;
    int t = z >> 1, et = z & 1;
    const int* ei = et ? ei_da : ei_ad;
    int dst = ei[(t * 2 + 1) * KE + e];
    atomicAdd(&cnt[z * KN + dst], 1);
}

__global__ void scan_k(int* __restrict__ cnt, int* __restrict__ offs) {
    __shared__ int s[256];
    int z = blockIdx.x, tid = threadIdx.x;
    const int CH = (KN + 255) / 256;    // 79
    int n0 = tid * CH;
    int lim = n0 < KN ? min(CH, KN - n0) : 0;
    long base = (long)z * KN + n0;
    int sum = 0;
    for (int i = 0; i < lim; ++i) sum += cnt[base + i];
    s[tid] = sum;
    __syncthreads();
    for (int off = 1; off < 256; off <<= 1) {
        int v = (tid >= off) ? s[tid - off] : 0;
        __syncthreads();
        s[tid] += v;
        __syncthreads();
    }
    int run = s[tid] - sum;             // exclusive prefix
    for (int i = 0; i < lim; ++i) {
        int c = cnt[base + i];
        offs[(long)z * (KN + 1) + n0 + i] = run;
        cnt[base + i] = run;            // becomes fill cursor
        run += c;
    }
    if (tid == 0) offs[(long)z * (KN + 1) + KN] = KE;
}

__global__ void fill_k(const int* __restrict__ ei_ad, const int* __restrict__ ei_da,
                       int* __restrict__ cur, int2* __restrict__ pes) {
    int e = blockIdx.x * 256 + threadIdx.x;
    int z = blockIdx.y;
    if (e >= KE) return;
    int t = z >> 1, et = z & 1;
    const int* ei = et ? ei_da : ei_ad;
    int src = ei[(t * 2 + 0) * KE + e];
    int dst = ei[(t * 2 + 1) * KE + e];
    int pos = atomicAdd(&cur[z * KN + dst], 1);
    pes[(long)z * KE + pos] = make_int2(e, src);
}

// ---------------------------------------------------------------------------
// Aggregation: 32-lane group per node (8 nodes/block), 8-edge batches.
// ea read as bf16 rows ea_s[e] (random 256B but L3-resident, half bytes);
// x_src gathers random but L3-resident.  Output pre-split bf16 hi/lo.
// ---------------------------------------------------------------------------
__global__ __launch_bounds__(256)
void agg_k(const float* __restrict__ xa_base, long xa_ts,
           const float* __restrict__ xd_base, long xd_ts,
           const float* __restrict__ ea_ad, const float* __restrict__ ea_da,
           const float* __restrict__ eps_ad, const float* __restrict__ eps_da,
           const int* __restrict__ offs, const int2* __restrict__ pes,
           const unsigned short* __restrict__ ea_s,
           short* __restrict__ agg_hi, short* __restrict__ agg_lo,
           int l, int use_eas) {
    int z = blockIdx.y, t = z >> 1, et = z & 1;
    int li = threadIdx.x & 31;
    int node = blockIdx.x * 8 + (threadIdx.x >> 5);   // grid exact: KN/8

    const float* ea  = (et ? ea_da : ea_ad) + (long)t * KE * KH;
    const float* eps = et ? eps_da : eps_ad;
    const float* src = et ? (xd_base + t * xd_ts) : (xa_base + t * xa_ts);
    const float* dst = et ? (xa_base + t * xa_ts) : (xd_base + t * xd_ts);
    const int2*  pz  = pes + (long)z * KE;
    const unsigned short* ez = ea_s + (long)z * KE * KH;

    int beg = offs[(long)z * (KN + 1) + node];
    int end = offs[(long)z * (KN + 1) + node + 1];
    float scale = 1.0f + eps[t * KL + l];

    float4 dv = *(const float4*)(dst + (long)node * KH + li * 4);
    float4 acc = make_float4(0.f, 0.f, 0.f, 0.f);

    if (beg < end) {
        int last = end - 1;
        if (use_eas) {
            for (int i = beg; i < end; i += 8) {
                int2 pp[8];
                #pragma unroll
                for (int u = 0; u < 8; ++u) pp[u] = pz[min(i + u, last)];
                uint2 gg[8];
                #pragma unroll
                for (int u = 0; u < 8; ++u)
                    gg[u] = *(const uint2*)(ez + (long)pp[u].x * KH + li * 4);
                float4 xx[8];
                #pragma unroll
                for (int u = 0; u < 8; ++u)
                    xx[u] = *(const float4*)(src + (long)pp[u].y * KH + li * 4);
                #pragma unroll
                for (int u = 0; u < 8; ++u) {
                    float m = (i + u <= last) ? 1.0f : 0.0f;
                    float f0 = __uint_as_float(gg[u].x << 16);
                    float f1 = __uint_as_float(gg[u].x & 0xffff0000u);
                    float f2 = __uint_as_float(gg[u].y << 16);
                    float f3 = __uint_as_float(gg[u].y & 0xffff0000u);
                    acc.x = fmaf(m, fmaxf(xx[u].x + f0, 0.f), acc.x);
                    acc.y = fmaf(m, fmaxf(xx[u].y + f1, 0.f), acc.y);
                    acc.z = fmaf(m, fmaxf(xx[u].z + f2, 0.f), acc.z);
                    acc.w = fmaf(m, fmaxf(xx[u].w + f3, 0.f), acc.w);
                }
            }
        } else {
            for (int i = beg; i < end; i += 4) {
                int i0 = min(i, last), i1 = min(i + 1, last),
                    i2 = min(i + 2, last), i3 = min(i + 3, last);
                int2 p0 = pz[i0], p1 = pz[i1], p2 = pz[i2], p3 = pz[i3];
                float4 e0 = *(const float4*)(ea + (long)p0.x * KH + li * 4);
                float4 e1 = *(const float4*)(ea + (long)p1.x * KH + li * 4);
                float4 e2 = *(const float4*)(ea + (long)p2.x * KH + li * 4);
                float4 e3 = *(const float4*)(ea + (long)p3.x * KH + li * 4);
                float4 x0 = *(const float4*)(src + (long)p0.y * KH + li * 4);
                float4 x1 = *(const float4*)(src + (long)p1.y * KH + li * 4);
                float4 x2 = *(const float4*)(src + (long)p2.y * KH + li * 4);
                float4 x3 = *(const float4*)(src + (long)p3.y * KH + li * 4);
                float4 es4[4] = {e0, e1, e2, e3};
                float4 xs[4] = {x0, x1, x2, x3};
                #pragma unroll
                for (int u = 0; u < 4; ++u) {
                    float m = (i + u <= last) ? 1.0f : 0.0f;
                    acc.x = fmaf(m, fmaxf(xs[u].x + es4[u].x, 0.f), acc.x);
                    acc.y = fmaf(m, fmaxf(xs[u].y + es4[u].y, 0.f), acc.y);
                    acc.z = fmaf(m, fmaxf(xs[u].z + es4[u].z, 0.f), acc.z);
                    acc.w = fmaf(m, fmaxf(xs[u].w + es4[u].w, 0.f), acc.w);
                }
            }
        }
    }

    float4 r;
    r.x = fmaf(scale, dv.x, acc.x);
    r.y = fmaf(scale, dv.y, acc.y);
    r.z = fmaf(scale, dv.z, acc.z);
    r.w = fmaf(scale, dv.w, acc.w);

    unsigned short h0 = (unsigned short)bf16rn(r.x);
    unsigned short h1 = (unsigned short)bf16rn(r.y);
    unsigned short h2 = (unsigned short)bf16rn(r.z);
    unsigned short h3 = (unsigned short)bf16rn(r.w);
    unsigned short l0 = (unsigned short)bf16rn(r.x - bf16tof((short)h0));
    unsigned short l1 = (unsigned short)bf16rn(r.y - bf16tof((short)h1));
    unsigned short l2 = (unsigned short)bf16rn(r.z - bf16tof((short)h2));
    unsigned short l3 = (unsigned short)bf16rn(r.w - bf16tof((short)h3));
    long o = ((long)z * KN + node) * KH + li * 4;
    *(uint2*)(agg_hi + o) = make_uint2(((unsigned)h1 << 16) | h0, ((unsigned)h3 << 16) | h2);
    *(uint2*)(agg_lo + o) = make_uint2(((unsigned)l1 << 16) | l0, ((unsigned)l3 << 16) | l2);
}

// ---------------------------------------------------------------------------
// W pre-split: wsp[((mat*2+h)*4 + kc)*4096 + col*32 + kk], k = kc*32+kk.
// ---------------------------------------------------------------------------
__global__ __launch_bounds__(256)
void wsplit_k(const float* __restrict__ w1_ad, const float* __restrict__ w1_da,
              const float* __restrict__ w2_ad, const float* __restrict__ w2_da,
              short* __restrict__ wsp) {
    int mat = blockIdx.x >> 3, part = blockIdx.x & 7;   // mat 0..31
    int arr = mat >> 3, rem = mat & 7;   // rem = t*2+l
    const float* src = (arr == 0 ? w1_ad : arr == 1 ? w1_da : arr == 2 ? w2_ad : w2_da)
                       + (long)rem * KH * KH;
    #pragma unroll
    for (int p = 0; p < 8; ++p) {
        int idx = part * 2048 + p * 256 + threadIdx.x;  // 16384 elems total
        int k = idx >> 7, c = idx & 127;
        float v = src[idx];
        short hi = bf16rn(v);
        short lo = bf16rn(v - bf16tof(hi));
        int chunk = k >> 5, kk = k & 31;
        long ohi = ((long)(mat * 2 + 0) * 4 + chunk) * 4096 + c * 32 + kk;
        long olo = ((long)(mat * 2 + 1) * 4 + chunk) * 4096 + c * 32 + kk;
        wsp[ohi] = hi;
        wsp[olo] = lo;
    }
}

// ---------------------------------------------------------------------------
// Zero-LDS MFMA GEMM (3-term bf16-split): out = [relu](H @ W + b).
// A/B fragments loaded straight from global (hi/lo inputs + pre-transposed
// wsp), all L2/L3-resident.  Operand-swapped (W in A-slot) -> coalesced
// epilogue.  mode 0: write hi/lo bf16 IN-PLACE over the inputs (barrier
// before epilogue protects intra-block readers).  mode 1: fp32 to d_out.
// ---------------------------------------------------------------------------
__global__ __launch_bounds__(256)
void gemm_k(const short* in_hi, const short* in_lo,
            const short* __restrict__ wsp,
            const float* __restrict__ b_ad, const float* __restrict__ b_da,
            short* out_hi, short* out_lo, float* __restrict__ d_out,
            int l, int which, int relu, int mode) {
    int z = blockIdx.y, t = z >> 1, et = z & 1;
    int tid = threadIdx.x;
    int mat = (which * 2 + et) * 8 + t * 2 + l;
    const short* ih = in_hi + (long)z * KN * KH;
    const short* il = in_lo + (long)z * KN * KH;
    const float* Bp = (et ? b_da : b_ad) + (long)(t * KL + l) * KH;
    int r0 = blockIdx.x * 128;

    int lane = tid & 63, wid = tid >> 6;
    int wr = wid >> 1, wc = wid & 1;
    int lrow = lane & 15, lq = lane >> 4;

    f32x4 acc[4][4];
    #pragma unroll
    for (int i = 0; i < 4; ++i)
        #pragma unroll
        for (int j = 0; j < 4; ++j) acc[i][j] = (f32x4){0.f, 0.f, 0.f, 0.f};

    #pragma unroll
    for (int kc = 0; kc < 4; ++kc) {
        const short* whp = wsp + ((long)(mat * 2 + 0) * 4 + kc) * 4096;
        const short* wlp = wsp + ((long)(mat * 2 + 1) * 4 + kc) * 4096;
        short8v bhi[4], blo[4];
        #pragma unroll
        for (int j = 0; j < 4; ++j) {
            int off = (wc * 64 + j * 16 + lrow) * 32 + lq * 8;
            bhi[j] = *(const short8v*)(whp + off);
            blo[j] = *(const short8v*)(wlp + off);
        }
        #pragma unroll
        for (int i = 0; i < 4; ++i) {
            int row = min(r0 + wr * 64 + i * 16 + lrow, KN - 1);
            long o = (long)row * KH + kc * 32 + lq * 8;
            short8v ahi = *(const short8v*)(ih + o);
            short8v alo = *(const short8v*)(il + o);
            #pragma unroll
            for (int j = 0; j < 4; ++j) {
                acc[i][j] = __builtin_amdgcn_mfma_f32_16x16x32_bf16(bhi[j], ahi, acc[i][j], 0, 0, 0);
                acc[i][j] = __builtin_amdgcn_mfma_f32_16x16x32_bf16(blo[j], ahi, acc[i][j], 0, 0, 0);
                acc[i][j] = __builtin_amdgcn_mfma_f32_16x16x32_bf16(bhi[j], alo, acc[i][j], 0, 0, 0);
            }
        }
    }

    __syncthreads();    // all reads done before in-place overwrite (mode 0)

    #pragma unroll
    for (int i = 0; i < 4; ++i) {
        int node = r0 + wr * 64 + i * 16 + lrow;
        if (node >= KN) continue;
        #pragma unroll
        for (int j = 0; j < 4; ++j) {
            int col = wc * 64 + j * 16 + lq * 4;
            float4 b4 = *(const float4*)&Bp[col];
            f32x4 a = acc[i][j];
            float4 v;
            v.x = a[0] + b4.x; v.y = a[1] + b4.y;
            v.z = a[2] + b4.z; v.w = a[3] + b4.w;
            if (relu) {
                v.x = fmaxf(v.x, 0.f); v.y = fmaxf(v.y, 0.f);
                v.z = fmaxf(v.z, 0.f); v.w = fmaxf(v.w, 0.f);
            }
            if (mode == 0) {
                unsigned short h0 = (unsigned short)bf16rn(v.x);
                unsigned short h1 = (unsigned short)bf16rn(v.y);
                unsigned short h2 = (unsigned short)bf16rn(v.z);
                unsigned short h3 = (unsigned short)bf16rn(v.w);
                unsigned short q0 = (unsigned short)bf16rn(v.x - bf16tof((short)h0));
                unsigned short q1 = (unsigned short)bf16rn(v.y - bf16tof((short)h1));
                unsigned short q2 = (unsigned short)bf16rn(v.z - bf16tof((short)h2));
                unsigned short q3 = (unsigned short)bf16rn(v.w - bf16tof((short)h3));
                long o = ((long)z * KN + node) * KH + col;
                *(uint2*)(out_hi + o) = make_uint2(((unsigned)h1 << 16) | h0,
                                                   ((unsigned)h3 << 16) | h2);
                *(uint2*)(out_lo + o) = make_uint2(((unsigned)q1 << 16) | q0,
                                                   ((unsigned)q3 << 16) | q2);
            } else {
                long off = (long)t * KNT * KH + (et == 0 ? (long)KN * KH : 0)
                         + (long)node * KH + col;
                *(float4*)&d_out[off] = v;
            }
        }
    }
}

// ---------------------------------------------------------------------------
extern "C" void kernel_launch(void* const* d_in, const int* in_sizes, int n_in,
                              void* d_out_v, int out_size, void* d_ws, size_t ws_size,
                              hipStream_t stream) {
    const float* x_a    = (const float*)d_in[0];
    const float* x_d    = (const float*)d_in[1];
    const float* ea_ad  = (const float*)d_in[2];
    const float* ea_da  = (const float*)d_in[3];
    const int*   ei_ad  = (const int*)d_in[4];
    const int*   ei_da  = (const int*)d_in[5];
    const float* w1_ad  = (const float*)d_in[6];
    const float* b1_ad  = (const float*)d_in[7];
    const float* w2_ad  = (const float*)d_in[8];
    const float* b2_ad  = (const float*)d_in[9];
    const float* w1_da  = (const float*)d_in[11];
    const float* b1_da  = (const float*)d_in[12];
    const float* w2_da  = (const float*)d_in[13];
    const float* b2_da  = (const float*)d_in[14];
    const float* eps_ad = (const float*)d_in[10];
    const float* eps_da = (const float*)d_in[15];
    float* out = (float*)d_out_v;

    // workspace layout
    size_t nHL = (size_t)8 * KN * KH;                        // shorts
    short* agg_hi = (short*)d_ws;
    short* agg_lo = agg_hi + nHL;
    int*   offs   = (int*)(agg_lo + nHL);                    // 8*(KN+1)
    int*   cur    = offs + (size_t)8 * (KN + 1);             // 8*KN
    int2*  pes    = (int2*)(cur + (size_t)8 * KN);           // 8*KE
    short* wsp    = (short*)(pes + (size_t)8 * KE);          // 1,048,576 shorts
    unsigned short* ea_s = (unsigned short*)(wsp + (size_t)32 * 2 * 4 * 4096);
    size_t need = (size_t)((char*)(ea_s + (size_t)8 * KE * KH) - (char*)d_ws);
    int use_eas = (ws_size >= need) ? 1 : 0;

    hipMemsetAsync(cur, 0, (size_t)8 * KN * sizeof(int), stream);
    wsplit_k<<<256, 256, 0, stream>>>(w1_ad, w1_da, w2_ad, w2_da, wsp);
    if (use_eas)
        compress_k<<<dim3(2500, 8), 256, 0, stream>>>(ea_ad, ea_da, ea_s);

    dim3 eg((KE + 255) / 256, 8);
    count_k<<<eg, 256, 0, stream>>>(ei_ad, ei_da, cur);
    scan_k<<<8, 256, 0, stream>>>(cur, offs);
    fill_k<<<eg, 256, 0, stream>>>(ei_ad, ei_da, cur, pes);

    dim3 ag(KN / 8, 8);                  // 2500 x 8, exact
    dim3 gg((KN + 127) / 128, 8);        // 157 x 8

    for (int l = 0; l < KL; ++l) {
        const float* xab; long xats;
        const float* xdb; long xdts;
        if (l == 0) {
            xab = x_a; xats = (long)KN * KH;
            xdb = x_d; xdts = (long)KN * KH;
        } else {
            xab = out;                 xats = (long)KNT * KH;
            xdb = out + (long)KN * KH; xdts = (long)KNT * KH;
        }
        agg_k<<<ag, 256, 0, stream>>>(xab, xats, xdb, xdts,
                                      ea_ad, ea_da, eps_ad, eps_da,
                                      offs, pes, ea_s, agg_hi, agg_lo, l, use_eas);
        // mid = relu(H @ w1 + b1): hi/lo in-place over agg_hi/agg_lo
        gemm_k<<<gg, 256, 0, stream>>>(agg_hi, agg_lo, wsp, b1_ad, b1_da,
                                       agg_hi, agg_lo, out, l, 0, 1, 0);
        // x_new = mid @ w2 + b2 (+relu between layers) -> d_out fp32
        gemm_k<<<gg, 256, 0, stream>>>(agg_hi, agg_lo, wsp, b2_ad, b2_da,
                                       agg_hi, agg_lo, out, l, 1, (l == 0) ? 1 : 0, 1);
    }
}

// Round 11
// 675.412 us; speedup vs baseline: 1.1010x; 1.1010x over previous
//
#include <hip/hip_runtime.h>

#define KT 4
#define KN 20000        // NA == ND == 20000
#define KE 100000
#define KH 128
#define KL 2
#define KNT 40000       // NA + ND

typedef __attribute__((ext_vector_type(8))) short short8v;
typedef __attribute__((ext_vector_type(4))) float f32x4;

__device__ __forceinline__ short bf16rn(float x) {
    unsigned u = __float_as_uint(x);
    u = (u + 0x7fffu + ((u >> 16) & 1u)) >> 16;
    return (short)u;
}
__device__ __forceinline__ float bf16tof(short h) {
    return __uint_as_float(((unsigned)(unsigned short)h) << 16);
}

// ---------------------------------------------------------------------------
// CSR build: counts -> scan -> fill (packed (edge, src) pairs).
// ---------------------------------------------------------------------------
__global__ void count_k(const int* __restrict__ ei_ad, const int* __restrict__ ei_da,
                        int* __restrict__ cnt) {
    int e = blockIdx.x * 256 + threadIdx.x;
    int z = blockIdx.y;                 // z = t*2 + et
    if (e >= KE) return;
    int t = z >> 1, et = z & 1;
    const int* ei = et ? ei_da : ei_ad;
    int dst = ei[(t * 2 + 1) * KE + e];
    atomicAdd(&cnt[z * KN + dst], 1);
}

__global__ void scan_k(int* __restrict__ cnt, int* __restrict__ offs) {
    __shared__ int s[256];
    int z = blockIdx.x, tid = threadIdx.x;
    const int CH = (KN + 255) / 256;    // 79
    int n0 = tid * CH;
    int lim = n0 < KN ? min(CH, KN - n0) : 0;
    long base = (long)z * KN + n0;
    int sum = 0;
    for (int i = 0; i < lim; ++i) sum += cnt[base + i];
    s[tid] = sum;
    __syncthreads();
    for (int off = 1; off < 256; off <<= 1) {
        int v = (tid >= off) ? s[tid - off] : 0;
        __syncthreads();
        s[tid] += v;
        __syncthreads();
    }
    int run = s[tid] - sum;             // exclusive prefix
    for (int i = 0; i < lim; ++i) {
        int c = cnt[base + i];
        offs[(long)z * (KN + 1) + n0 + i] = run;
        cnt[base + i] = run;            // becomes fill cursor
        run += c;
    }
    if (tid == 0) offs[(long)z * (KN + 1) + KN] = KE;
}

__global__ void fill_k(const int* __restrict__ ei_ad, const int* __restrict__ ei_da,
                       int* __restrict__ cur, int2* __restrict__ pes) {
    int e = blockIdx.x * 256 + threadIdx.x;
    int z = blockIdx.y;
    if (e >= KE) return;
    int t = z >> 1, et = z & 1;
    const int* ei = et ? ei_da : ei_ad;
    int src = ei[(t * 2 + 0) * KE + e];
    int dst = ei[(t * 2 + 1) * KE + e];
    int pos = atomicAdd(&cur[z * KN + dst], 1);
    pes[(long)z * KE + pos] = make_int2(e, src);
}

// ---------------------------------------------------------------------------
// Aggregation: 32-lane group per node (8 nodes/block).
// l==0 (csr_mode=1): gather ea fp32 rows (random, unavoidable once) AND emit
//   bf16 copy at CSR position i (sequential 256B-row writes) for layer 1.
// l==1 (csr_mode=2): read ea_csr[i] SEQUENTIALLY as bf16 -> streams at HBM
//   rate, half the bytes; only x gathers remain random (L3-resident).
// Output pre-split bf16 hi/lo for the zero-LDS MFMA GEMM.
// ---------------------------------------------------------------------------
__global__ __launch_bounds__(256)
void agg_k(const float* __restrict__ xa_base, long xa_ts,
           const float* __restrict__ xd_base, long xd_ts,
           const float* __restrict__ ea_ad, const float* __restrict__ ea_da,
           const float* __restrict__ eps_ad, const float* __restrict__ eps_da,
           const int* __restrict__ offs, const int2* __restrict__ pes,
           unsigned short* __restrict__ ea_csr,
           short* __restrict__ agg_hi, short* __restrict__ agg_lo,
           int l, int csr_mode) {
    int z = blockIdx.y, t = z >> 1, et = z & 1;
    int li = threadIdx.x & 31;
    int node = blockIdx.x * 8 + (threadIdx.x >> 5);   // grid exact: KN/8

    const float* ea  = (et ? ea_da : ea_ad) + (long)t * KE * KH;
    const float* eps = et ? eps_da : eps_ad;
    const float* src = et ? (xd_base + t * xd_ts) : (xa_base + t * xa_ts);
    const float* dst = et ? (xa_base + t * xa_ts) : (xd_base + t * xd_ts);
    const int2*  pz  = pes + (long)z * KE;
    unsigned short* ec = ea_csr + (long)z * KE * KH;

    int beg = offs[(long)z * (KN + 1) + node];
    int end = offs[(long)z * (KN + 1) + node + 1];
    float scale = 1.0f + eps[t * KL + l];

    float4 dv = *(const float4*)(dst + (long)node * KH + li * 4);
    float4 acc = make_float4(0.f, 0.f, 0.f, 0.f);

    if (beg < end) {
        int last = end - 1;
        if (csr_mode == 2) {
            // layer 1: ea from sequential bf16 CSR copy
            for (int i = beg; i < end; i += 8) {
                int idx[8]; int2 pp[8];
                #pragma unroll
                for (int u = 0; u < 8; ++u) idx[u] = min(i + u, last);
                #pragma unroll
                for (int u = 0; u < 8; ++u) pp[u] = pz[idx[u]];
                uint2 gg[8];
                #pragma unroll
                for (int u = 0; u < 8; ++u)
                    gg[u] = *(const uint2*)(ec + (long)idx[u] * KH + li * 4);
                float4 xx[8];
                #pragma unroll
                for (int u = 0; u < 8; ++u)
                    xx[u] = *(const float4*)(src + (long)pp[u].y * KH + li * 4);
                #pragma unroll
                for (int u = 0; u < 8; ++u) {
                    float m = (i + u <= last) ? 1.0f : 0.0f;
                    float f0 = __uint_as_float(gg[u].x << 16);
                    float f1 = __uint_as_float(gg[u].x & 0xffff0000u);
                    float f2 = __uint_as_float(gg[u].y << 16);
                    float f3 = __uint_as_float(gg[u].y & 0xffff0000u);
                    acc.x = fmaf(m, fmaxf(xx[u].x + f0, 0.f), acc.x);
                    acc.y = fmaf(m, fmaxf(xx[u].y + f1, 0.f), acc.y);
                    acc.z = fmaf(m, fmaxf(xx[u].z + f2, 0.f), acc.z);
                    acc.w = fmaf(m, fmaxf(xx[u].w + f3, 0.f), acc.w);
                }
            }
        } else {
            // layer 0: ea fp32 random gathers (+ optional bf16 CSR emit)
            for (int i = beg; i < end; i += 4) {
                int i0 = min(i, last), i1 = min(i + 1, last),
                    i2 = min(i + 2, last), i3 = min(i + 3, last);
                int2 p0 = pz[i0], p1 = pz[i1], p2 = pz[i2], p3 = pz[i3];
                float4 e0 = *(const float4*)(ea + (long)p0.x * KH + li * 4);
                float4 e1 = *(const float4*)(ea + (long)p1.x * KH + li * 4);
                float4 e2 = *(const float4*)(ea + (long)p2.x * KH + li * 4);
                float4 e3 = *(const float4*)(ea + (long)p3.x * KH + li * 4);
                float4 x0 = *(const float4*)(src + (long)p0.y * KH + li * 4);
                float4 x1 = *(const float4*)(src + (long)p1.y * KH + li * 4);
                float4 x2 = *(const float4*)(src + (long)p2.y * KH + li * 4);
                float4 x3 = *(const float4*)(src + (long)p3.y * KH + li * 4);
                float4 es4[4] = {e0, e1, e2, e3};
                float4 xs[4] = {x0, x1, x2, x3};
                #pragma unroll
                for (int u = 0; u < 4; ++u) {
                    float m = (i + u <= last) ? 1.0f : 0.0f;
                    acc.x = fmaf(m, fmaxf(xs[u].x + es4[u].x, 0.f), acc.x);
                    acc.y = fmaf(m, fmaxf(xs[u].y + es4[u].y, 0.f), acc.y);
                    acc.z = fmaf(m, fmaxf(xs[u].z + es4[u].z, 0.f), acc.z);
                    acc.w = fmaf(m, fmaxf(xs[u].w + es4[u].w, 0.f), acc.w);
                }
                if (csr_mode == 1) {
                    // sequential bf16 emit for layer 1 (predicated, no dups)
                    #pragma unroll
                    for (int u = 0; u < 4; ++u) {
                        if (i + u <= last) {
                            float4 e4 = es4[u];
                            unsigned w0 = (unsigned)(unsigned short)bf16rn(e4.x)
                                        | ((unsigned)(unsigned short)bf16rn(e4.y) << 16);
                            unsigned w1 = (unsigned)(unsigned short)bf16rn(e4.z)
                                        | ((unsigned)(unsigned short)bf16rn(e4.w) << 16);
                            *(uint2*)(ec + (long)(i + u) * KH + li * 4) = make_uint2(w0, w1);
                        }
                    }
                }
            }
        }
    }

    float4 r;
    r.x = fmaf(scale, dv.x, acc.x);
    r.y = fmaf(scale, dv.y, acc.y);
    r.z = fmaf(scale, dv.z, acc.z);
    r.w = fmaf(scale, dv.w, acc.w);

    unsigned short h0 = (unsigned short)bf16rn(r.x);
    unsigned short h1 = (unsigned short)bf16rn(r.y);
    unsigned short h2 = (unsigned short)bf16rn(r.z);
    unsigned short h3 = (unsigned short)bf16rn(r.w);
    unsigned short l0 = (unsigned short)bf16rn(r.x - bf16tof((short)h0));
    unsigned short l1 = (unsigned short)bf16rn(r.y - bf16tof((short)h1));
    unsigned short l2 = (unsigned short)bf16rn(r.z - bf16tof((short)h2));
    unsigned short l3 = (unsigned short)bf16rn(r.w - bf16tof((short)h3));
    long o = ((long)z * KN + node) * KH + li * 4;
    *(uint2*)(agg_hi + o) = make_uint2(((unsigned)h1 << 16) | h0, ((unsigned)h3 << 16) | h2);
    *(uint2*)(agg_lo + o) = make_uint2(((unsigned)l1 << 16) | l0, ((unsigned)l3 << 16) | l2);
}

// ---------------------------------------------------------------------------
// W pre-split: wsp[((mat*2+h)*4 + kc)*4096 + col*32 + kk], k = kc*32+kk.
// ---------------------------------------------------------------------------
__global__ __launch_bounds__(256)
void wsplit_k(const float* __restrict__ w1_ad, const float* __restrict__ w1_da,
              const float* __restrict__ w2_ad, const float* __restrict__ w2_da,
              short* __restrict__ wsp) {
    int mat = blockIdx.x >> 3, part = blockIdx.x & 7;   // mat 0..31
    int arr = mat >> 3, rem = mat & 7;   // rem = t*2+l
    const float* src = (arr == 0 ? w1_ad : arr == 1 ? w1_da : arr == 2 ? w2_ad : w2_da)
                       + (long)rem * KH * KH;
    #pragma unroll
    for (int p = 0; p < 8; ++p) {
        int idx = part * 2048 + p * 256 + threadIdx.x;  // 16384 elems total
        int k = idx >> 7, c = idx & 127;
        float v = src[idx];
        short hi = bf16rn(v);
        short lo = bf16rn(v - bf16tof(hi));
        int chunk = k >> 5, kk = k & 31;
        long ohi = ((long)(mat * 2 + 0) * 4 + chunk) * 4096 + c * 32 + kk;
        long olo = ((long)(mat * 2 + 1) * 4 + chunk) * 4096 + c * 32 + kk;
        wsp[ohi] = hi;
        wsp[olo] = lo;
    }
}

// ---------------------------------------------------------------------------
// Zero-LDS MFMA GEMM (3-term bf16-split): out = [relu](H @ W + b).
// A/B fragments loaded straight from global (hi/lo inputs + pre-transposed
// wsp), all L2/L3-resident.  Operand-swapped (W in A-slot) -> coalesced
// epilogue.  mode 0: write hi/lo bf16 IN-PLACE over the inputs (barrier
// before epilogue protects intra-block readers).  mode 1: fp32 to d_out.
// ---------------------------------------------------------------------------
__global__ __launch_bounds__(256)
void gemm_k(const short* in_hi, const short* in_lo,
            const short* __restrict__ wsp,
            const float* __restrict__ b_ad, const float* __restrict__ b_da,
            short* out_hi, short* out_lo, float* __restrict__ d_out,
            int l, int which, int relu, int mode) {
    int z = blockIdx.y, t = z >> 1, et = z & 1;
    int tid = threadIdx.x;
    int mat = (which * 2 + et) * 8 + t * 2 + l;
    const short* ih = in_hi + (long)z * KN * KH;
    const short* il = in_lo + (long)z * KN * KH;
    const float* Bp = (et ? b_da : b_ad) + (long)(t * KL + l) * KH;
    int r0 = blockIdx.x * 128;

    int lane = tid & 63, wid = tid >> 6;
    int wr = wid >> 1, wc = wid & 1;
    int lrow = lane & 15, lq = lane >> 4;

    f32x4 acc[4][4];
    #pragma unroll
    for (int i = 0; i < 4; ++i)
        #pragma unroll
        for (int j = 0; j < 4; ++j) acc[i][j] = (f32x4){0.f, 0.f, 0.f, 0.f};

    #pragma unroll
    for (int kc = 0; kc < 4; ++kc) {
        const short* whp = wsp + ((long)(mat * 2 + 0) * 4 + kc) * 4096;
        const short* wlp = wsp + ((long)(mat * 2 + 1) * 4 + kc) * 4096;
        short8v bhi[4], blo[4];
        #pragma unroll
        for (int j = 0; j < 4; ++j) {
            int off = (wc * 64 + j * 16 + lrow) * 32 + lq * 8;
            bhi[j] = *(const short8v*)(whp + off);
            blo[j] = *(const short8v*)(wlp + off);
        }
        #pragma unroll
        for (int i = 0; i < 4; ++i) {
            int row = min(r0 + wr * 64 + i * 16 + lrow, KN - 1);
            long o = (long)row * KH + kc * 32 + lq * 8;
            short8v ahi = *(const short8v*)(ih + o);
            short8v alo = *(const short8v*)(il + o);
            #pragma unroll
            for (int j = 0; j < 4; ++j) {
                acc[i][j] = __builtin_amdgcn_mfma_f32_16x16x32_bf16(bhi[j], ahi, acc[i][j], 0, 0, 0);
                acc[i][j] = __builtin_amdgcn_mfma_f32_16x16x32_bf16(blo[j], ahi, acc[i][j], 0, 0, 0);
                acc[i][j] = __builtin_amdgcn_mfma_f32_16x16x32_bf16(bhi[j], alo, acc[i][j], 0, 0, 0);
            }
        }
    }

    __syncthreads();    // all reads done before in-place overwrite (mode 0)

    #pragma unroll
    for (int i = 0; i < 4; ++i) {
        int node = r0 + wr * 64 + i * 16 + lrow;
        if (node >= KN) continue;
        #pragma unroll
        for (int j = 0; j < 4; ++j) {
            int col = wc * 64 + j * 16 + lq * 4;
            float4 b4 = *(const float4*)&Bp[col];
            f32x4 a = acc[i][j];
            float4 v;
            v.x = a[0] + b4.x; v.y = a[1] + b4.y;
            v.z = a[2] + b4.z; v.w = a[3] + b4.w;
            if (relu) {
                v.x = fmaxf(v.x, 0.f); v.y = fmaxf(v.y, 0.f);
                v.z = fmaxf(v.z, 0.f); v.w = fmaxf(v.w, 0.f);
            }
            if (mode == 0) {
                unsigned short h0 = (unsigned short)bf16rn(v.x);
                unsigned short h1 = (unsigned short)bf16rn(v.y);
                unsigned short h2 = (unsigned short)bf16rn(v.z);
                unsigned short h3 = (unsigned short)bf16rn(v.w);
                unsigned short q0 = (unsigned short)bf16rn(v.x - bf16tof((short)h0));
                unsigned short q1 = (unsigned short)bf16rn(v.y - bf16tof((short)h1));
                unsigned short q2 = (unsigned short)bf16rn(v.z - bf16tof((short)h2));
                unsigned short q3 = (unsigned short)bf16rn(v.w - bf16tof((short)h3));
                long o = ((long)z * KN + node) * KH + col;
                *(uint2*)(out_hi + o) = make_uint2(((unsigned)h1 << 16) | h0,
                                                   ((unsigned)h3 << 16) | h2);
                *(uint2*)(out_lo + o) = make_uint2(((unsigned)q1 << 16) | q0,
                                                   ((unsigned)q3 << 16) | q2);
            } else {
                long off = (long)t * KNT * KH + (et == 0 ? (long)KN * KH : 0)
                         + (long)node * KH + col;
                *(float4*)&d_out[off] = v;
            }
        }
    }
}

// ---------------------------------------------------------------------------
extern "C" void kernel_launch(void* const* d_in, const int* in_sizes, int n_in,
                              void* d_out_v, int out_size, void* d_ws, size_t ws_size,
                              hipStream_t stream) {
    const float* x_a    = (const float*)d_in[0];
    const float* x_d    = (const float*)d_in[1];
    const float* ea_ad  = (const float*)d_in[2];
    const float* ea_da  = (const float*)d_in[3];
    const int*   ei_ad  = (const int*)d_in[4];
    const int*   ei_da  = (const int*)d_in[5];
    const float* w1_ad  = (const float*)d_in[6];
    const float* b1_ad  = (const float*)d_in[7];
    const float* w2_ad  = (const float*)d_in[8];
    const float* b2_ad  = (const float*)d_in[9];
    const float* w1_da  = (const float*)d_in[11];
    const float* b1_da  = (const float*)d_in[12];
    const float* w2_da  = (const float*)d_in[13];
    const float* b2_da  = (const float*)d_in[14];
    const float* eps_ad = (const float*)d_in[10];
    const float* eps_da = (const float*)d_in[15];
    float* out = (float*)d_out_v;

    // workspace layout
    size_t nHL = (size_t)8 * KN * KH;                        // shorts
    short* agg_hi = (short*)d_ws;
    short* agg_lo = agg_hi + nHL;
    int*   offs   = (int*)(agg_lo + nHL);                    // 8*(KN+1)
    int*   cur    = offs + (size_t)8 * (KN + 1);             // 8*KN
    int2*  pes    = (int2*)(cur + (size_t)8 * KN);           // 8*KE
    short* wsp    = (short*)(pes + (size_t)8 * KE);          // 1,048,576 shorts
    unsigned short* ea_csr = (unsigned short*)(wsp + (size_t)32 * 2 * 4 * 4096);
    size_t need = (size_t)((char*)(ea_csr + (size_t)8 * KE * KH) - (char*)d_ws);
    int have_csr = (ws_size >= need) ? 1 : 0;

    hipMemsetAsync(cur, 0, (size_t)8 * KN * sizeof(int), stream);
    wsplit_k<<<256, 256, 0, stream>>>(w1_ad, w1_da, w2_ad, w2_da, wsp);

    dim3 eg((KE + 255) / 256, 8);
    count_k<<<eg, 256, 0, stream>>>(ei_ad, ei_da, cur);
    scan_k<<<8, 256, 0, stream>>>(cur, offs);
    fill_k<<<eg, 256, 0, stream>>>(ei_ad, ei_da, cur, pes);

    dim3 ag(KN / 8, 8);                  // 2500 x 8, exact
    dim3 gg((KN + 127) / 128, 8);        // 157 x 8

    for (int l = 0; l < KL; ++l) {
        const float* xab; long xats;
        const float* xdb; long xdts;
        if (l == 0) {
            xab = x_a; xats = (long)KN * KH;
            xdb = x_d; xdts = (long)KN * KH;
        } else {
            xab = out;                 xats = (long)KNT * KH;
            xdb = out + (long)KN * KH; xdts = (long)KNT * KH;
        }
        int csr_mode = have_csr ? (l == 0 ? 1 : 2) : 0;
        agg_k<<<ag, 256, 0, stream>>>(xab, xats, xdb, xdts,
                                      ea_ad, ea_da, eps_ad, eps_da,
                                      offs, pes, ea_csr, agg_hi, agg_lo,
                                      l, csr_mode);
        // mid = relu(H @ w1 + b1): hi/lo in-place over agg_hi/agg_lo
        gemm_k<<<gg, 256, 0, stream>>>(agg_hi, agg_lo, wsp, b1_ad, b1_da,
                                       agg_hi, agg_lo, out, l, 0, 1, 0);
        // x_new = mid @ w2 + b2 (+relu between layers) -> d_out fp32
        gemm_k<<<gg, 256, 0, stream>>>(agg_hi, agg_lo, wsp, b2_ad, b2_da,
                                       agg_hi, agg_lo, out, l, 1, (l == 0) ? 1 : 0, 1);
    }
}